// Round 8
// baseline (205.242 us; speedup 1.0000x reference)
//
#include <hip/hip_runtime.h>

#define N_NODES 25000
#define N_EDGES 200000
#define NC 32
#define DMAX 64            // bucket capacity; degrees are Poisson(8), max ~25

typedef unsigned int u32;
typedef u32   u32x4 __attribute__((ext_vector_type(4)));
typedef u32   u32x2 __attribute__((ext_vector_type(2)));
typedef float f32x2 __attribute__((ext_vector_type(2)));
typedef float f32x4 __attribute__((ext_vector_type(4)));
// 4-byte-aligned views (HW supports dword-aligned x2/x4 accesses)
typedef u32x4 u32x4_a4 __attribute__((aligned(4)));
typedef u32x2 u32x2_a4 __attribute__((aligned(4)));
typedef f32x2 f32x2_a4 __attribute__((aligned(4)));
typedef f32x4 f32x4_a4 __attribute__((aligned(4)));

// ---------------------------------------------------------------------------
// Workspace layout (bytes)
//   Hm     : [25000][32 ch][14 ushort] bf16, 28 B/row, 896 B/node = 22,400,000
//   slots  : [25000][64] int2                                     = 12,800,000
//   cursor : [25000] int                                          =    100,000
// ---------------------------------------------------------------------------
static constexpr size_t HM_BYTES   = (size_t)N_NODES * NC * 28;        // 22,400,000
static constexpr size_t SLOTS_OFF  = HM_BYTES;
static constexpr size_t CURSOR_OFF = SLOTS_OFF + (size_t)N_NODES * DMAX * 8;
static constexpr size_t WS_NEEDED  = CURSOR_OFF + (size_t)N_NODES * 4; // ~35.3 MB

__device__ __forceinline__ unsigned short f2b(float f) {
    union { float f; unsigned u; } v; v.f = f;
    unsigned r = v.u + 0x7FFFu + ((v.u >> 16) & 1u);
    return (unsigned short)(r >> 16);
}
__device__ __forceinline__ float blo(u32 u) { return __uint_as_float(u << 16); }
__device__ __forceinline__ float bhi(u32 u) { return __uint_as_float(u & 0xFFFF0000u); }

// ---------------------------------------------------------------------------
// Per-edge contraction math (closed form of all einsum terms). Accumulates.
// ---------------------------------------------------------------------------
__device__ __forceinline__ void edge_contract(
    float H0v, const float H1v[3], const float H2v[9],
    float a0, const float a1[3], const float a2[9],
    float& acc0, float acc1[3], float acc2[9])
{
    const float t2 = a2[0] + a2[4] + a2[8];
    const float T2 = H2v[0] + H2v[4] + H2v[8];
    const float s  = a0 + t2;
    const float G  = H0v + T2;

    float sA[9], S2[9];
#pragma unroll
    for (int a = 0; a < 3; ++a)
#pragma unroll
        for (int b = 0; b < 3; ++b) {
            sA[a*3+b] = a2[a*3+b] + a2[b*3+a];
            S2[a*3+b] = H2v[a*3+b] + H2v[b*3+a];
        }

    float v0 = G * s;
#pragma unroll
    for (int a = 0; a < 3; ++a) v0 += H1v[a] * a1[a];
#pragma unroll
    for (int k = 0; k < 9; ++k) v0 += H2v[k] * sA[k];
    acc0 += v0;

#pragma unroll
    for (int a = 0; a < 3; ++a) {
        float v = G * a1[a] + H1v[a] * s;
#pragma unroll
        for (int b = 0; b < 3; ++b)
            v += sA[a*3+b] * H1v[b] + S2[a*3+b] * a1[b];
        acc1[a] += v;
    }

#pragma unroll
    for (int a = 0; a < 3; ++a)
#pragma unroll
        for (int b = 0; b < 3; ++b) {
            float v = G * a2[a*3+b] + H1v[a] * a1[b] + H2v[a*3+b] * s;
#pragma unroll
            for (int d = 0; d < 3; ++d)
                v += S2[a*3+d] * sA[d*3+b];
            acc2[a*3+b] += v;
        }
}

// ---------------------------------------------------------------------------
// Fused kernel: blocks [0,3125) = per-node channel mixing -> bf16 Hm
//               blocks [3125,3907) = bucket scatter of edges by send node
// cursor[] must be zeroed before this kernel (hipMemsetAsync).
// ---------------------------------------------------------------------------
__global__ __launch_bounds__(256) void mixscatter_kernel(
    const float* __restrict__ h0, const float* __restrict__ h1,
    const float* __restrict__ h2, const float* __restrict__ W,
    const int* __restrict__ ei,
    char* __restrict__ Hm, int2* __restrict__ slots, int* __restrict__ cursor)
{
    const int tid = threadIdx.x;

    if (blockIdx.x >= 3125) {            // ---- scatter part ----
        const int e = (blockIdx.x - 3125) * 256 + tid;
        if (e < N_EDGES) {
            const int send = ei[e];
            const int pos  = atomicAdd(&cursor[send], 1);
            if (pos < DMAX) {            // Poisson(8): deg>64 has P~1e-40
                int2 sl; sl.x = e; sl.y = ei[N_EDGES + e];
                slots[send * DMAX + pos] = sl;
            }
        }
        return;
    }

    // ---- mix part ----
    __shared__ float Wt[3 * 32 * 32];    // Wt[r][j][i] = W[r][i][j]
    __shared__ float h_lds[8 * 417];     // [node][j*13 + p]

    const int n0 = blockIdx.x * 8;

#pragma unroll
    for (int k = 0; k < 12; ++k) {
        int q = tid + k * 256;           // q = r*1024 + j*32 + i
        int r = q >> 10;
        int j = (q >> 5) & 31;
        int i = q & 31;
        Wt[q] = W[r * 1024 + i * 32 + j];
    }

    {
        int idx = tid;                   // h0: 256 floats
        h_lds[(idx >> 5) * 417 + (idx & 31) * 13 + 0] = h0[(size_t)n0 * 32 + idx];
    }
#pragma unroll
    for (int k = 0; k < 3; ++k) {        // h1: 768 floats
        int idx = tid + k * 256;
        int ln = idx / 96, rem = idx % 96;
        h_lds[ln * 417 + (rem / 3) * 13 + 1 + (rem % 3)] = h1[(size_t)n0 * 96 + idx];
    }
#pragma unroll
    for (int k = 0; k < 9; ++k) {        // h2: 2304 floats
        int idx = tid + k * 256;
        int ln = idx / 288, rem = idx % 288;
        h_lds[ln * 417 + (rem / 9) * 13 + 4 + (rem % 9)] = h2[(size_t)n0 * 288 + idx];
    }
    __syncthreads();

    const int ln = tid >> 5;
    const int i  = tid & 31;
    const int n  = n0 + ln;

    float acc[13];
#pragma unroll
    for (int p = 0; p < 13; ++p) acc[p] = 0.f;

#pragma unroll 4
    for (int j = 0; j < 32; ++j) {
        const float w0 = Wt[          j * 32 + i];
        const float w1 = Wt[1024 +    j * 32 + i];
        const float w2 = Wt[2048 +    j * 32 + i];
        const float* hv = &h_lds[ln * 417 + j * 13];
        acc[0] += w0 * hv[0];
#pragma unroll
        for (int p = 0; p < 3; ++p) acc[1 + p] += w1 * hv[1 + p];
#pragma unroll
        for (int p = 0; p < 9; ++p) acc[4 + p] += w2 * hv[4 + p];
    }

    // pack 13 bf16 into 28-B channel-major row
    unsigned short b[13];
#pragma unroll
    for (int p = 0; p < 13; ++p) b[p] = f2b(acc[p]);
    u32 w0 = (u32)b[0]  | ((u32)b[1]  << 16);
    u32 w1 = (u32)b[2]  | ((u32)b[3]  << 16);
    u32 w2 = (u32)b[4]  | ((u32)b[5]  << 16);
    u32 w3 = (u32)b[6]  | ((u32)b[7]  << 16);
    u32 w4 = (u32)b[8]  | ((u32)b[9]  << 16);
    u32 w5 = (u32)b[10] | ((u32)b[11] << 16);
    u32 w6 = (u32)b[12];

    char* dst = Hm + (size_t)n * 896 + i * 28;
    u32x4 q0; q0.x = w0; q0.y = w1; q0.z = w2; q0.w = w3;
    u32x2 q1; q1.x = w4; q1.y = w5;
    *(u32x4_a4*)dst        = q0;
    *(u32x2_a4*)(dst + 16) = q1;
    *(u32*)(dst + 24)      = w6;
}

// ---------------------------------------------------------------------------
// Gather: one WAVE per node; lane = channel + 32*par; par ∈ {0,1} walks
// alternating bucket slots; 13 shfl_xor(32) combines at the end.
// Plain loop (round-6 structure — explicit SW pipeline REGRESSED in round 7:
// VGPR 48->56, occupancy 36->30%, gather 54->61 µs. TLP covers the latency).
// Writes every output element exactly once (no zeroing of d_out needed).
// ---------------------------------------------------------------------------
__global__ __launch_bounds__(256, 8) void gather_kernel(
    const char* __restrict__ Hm, const int2* __restrict__ slots,
    const int* __restrict__ cursor,
    const float* __restrict__ ea0, const float* __restrict__ ea1,
    const float* __restrict__ ea2,
    float* __restrict__ out0, float* __restrict__ out1, float* __restrict__ out2)
{
    const int n    = blockIdx.x * 4 + (threadIdx.x >> 6);
    const int lane = threadIdx.x & 63;
    const int c    = lane & 31;
    const int par  = lane >> 5;

    const int draw = cursor[n];
    const int d    = draw < DMAX ? draw : DMAX;
    const int2* sb = slots + (u32)n * DMAX;
    const u32 c28  = (u32)c * 28u;

    float acc0 = 0.f, acc1[3] = {0.f, 0.f, 0.f};
    float acc2[9] = {0.f, 0.f, 0.f, 0.f, 0.f, 0.f, 0.f, 0.f, 0.f};

#pragma unroll 1
    for (int i = par; i < d; i += 2) {
        const int2 sl  = sb[i];
        const u32  e   = (u32)sl.x;

        // 28-B bf16 Hm row, 3 wide loads (u32 offset math)
        const char* hmp = Hm + ((u32)sl.y * 896u + c28);
        const u32x4 q0 = *(const u32x4_a4*)hmp;
        const u32x2 q1 = *(const u32x2_a4*)(hmp + 16);
        const u32   q2 = *(const u32*)(hmp + 24);

        const float H0v = blo(q0.x);
        float H1v[3], H2v[9];
        H1v[0] = bhi(q0.x); H1v[1] = blo(q0.y); H1v[2] = bhi(q0.y);
        H2v[0] = blo(q0.z); H2v[1] = bhi(q0.z); H2v[2] = blo(q0.w);
        H2v[3] = bhi(q0.w); H2v[4] = blo(q1.x); H2v[5] = bhi(q1.x);
        H2v[6] = blo(q1.y); H2v[7] = bhi(q1.y); H2v[8] = blo(q2);

        const float a0 = ea0[e];
        float a1[3], a2[9];
        {
            const f32x2 v = *(const f32x2_a4*)(ea1 + e * 3u);
            a1[0] = v.x; a1[1] = v.y; a1[2] = ea1[e * 3u + 2u];
            const f32x4 b0 = *(const f32x4_a4*)(ea2 + e * 9u);
            const f32x4 b1 = *(const f32x4_a4*)(ea2 + e * 9u + 4u);
            a2[0] = b0.x; a2[1] = b0.y; a2[2] = b0.z; a2[3] = b0.w;
            a2[4] = b1.x; a2[5] = b1.y; a2[6] = b1.z; a2[7] = b1.w;
            a2[8] = ea2[e * 9u + 8u];
        }

        edge_contract(H0v, H1v, H2v, a0, a1, a2, acc0, acc1, acc2);
    }

    // combine par=0 / par=1 halves
    acc0 += __shfl_xor(acc0, 32);
#pragma unroll
    for (int a = 0; a < 3; ++a) acc1[a] += __shfl_xor(acc1[a], 32);
#pragma unroll
    for (int k = 0; k < 9; ++k) acc2[k] += __shfl_xor(acc2[k], 32);

    if (par == 0) {
        const u32 base = (u32)n * 32u + (u32)c;
        out0[base] = acc0;
        // out1: 3 contiguous floats per lane
        f32x2 o1; o1.x = acc1[0]; o1.y = acc1[1];
        *(f32x2_a4*)(out1 + base * 3u) = o1;
        out1[base * 3u + 2u] = acc1[2];
        // out2: 9 contiguous floats per lane
        f32x4 oa; oa.x = acc2[0]; oa.y = acc2[1]; oa.z = acc2[2]; oa.w = acc2[3];
        f32x4 ob; ob.x = acc2[4]; ob.y = acc2[5]; ob.z = acc2[6]; ob.w = acc2[7];
        *(f32x4_a4*)(out2 + base * 9u)      = oa;
        *(f32x4_a4*)(out2 + base * 9u + 4u) = ob;
        out2[base * 9u + 8u] = acc2[8];
    }
}

// ---------------------------------------------------------------------------
// Fallback (no workspace): fused per-edge mixing + contraction + atomics
// ---------------------------------------------------------------------------
__global__ __launch_bounds__(256) void fused_edge_kernel(
    const float* __restrict__ h0, const float* __restrict__ h1,
    const float* __restrict__ h2, const float* __restrict__ W,
    const float* __restrict__ ea0, const float* __restrict__ ea1,
    const float* __restrict__ ea2, const int* __restrict__ ei,
    float* __restrict__ out0, float* __restrict__ out1, float* __restrict__ out2)
{
    __shared__ float Wt[3 * 32 * 32];
    __shared__ float h_lds[8 * 417];

    const int tid = threadIdx.x;
#pragma unroll
    for (int k = 0; k < 12; ++k) {
        int q = tid + k * 256;
        int r = q >> 10;
        int j = (q >> 5) & 31;
        int i = q & 31;
        Wt[q] = W[r * 1024 + i * 32 + j];
    }

    const int g = tid >> 5;
    const int c = tid & 31;
    const int e = blockIdx.x * 8 + g;
    const int send = ei[e];
    const int recv = ei[N_EDGES + e];

    h_lds[g * 417 + c * 13 + 0] = h0[(size_t)recv * 32 + c];
#pragma unroll
    for (int a = 0; a < 3; ++a)
        h_lds[g * 417 + c * 13 + 1 + a] = h1[(size_t)recv * 96 + c * 3 + a];
#pragma unroll
    for (int k = 0; k < 9; ++k)
        h_lds[g * 417 + c * 13 + 4 + k] = h2[(size_t)recv * 288 + c * 9 + k];
    __syncthreads();

    float acc[13];
#pragma unroll
    for (int p = 0; p < 13; ++p) acc[p] = 0.f;
#pragma unroll 4
    for (int j = 0; j < 32; ++j) {
        const float w0 = Wt[          j * 32 + c];
        const float w1 = Wt[1024 +    j * 32 + c];
        const float w2 = Wt[2048 +    j * 32 + c];
        const float* hv = &h_lds[g * 417 + j * 13];
        acc[0] += w0 * hv[0];
#pragma unroll
        for (int p = 0; p < 3; ++p) acc[1 + p] += w1 * hv[1 + p];
#pragma unroll
        for (int p = 0; p < 9; ++p) acc[4 + p] += w2 * hv[4 + p];
    }

    const float a0 = ea0[e];
    float a1[3], a2[9];
#pragma unroll
    for (int a = 0; a < 3; ++a) a1[a] = ea1[(size_t)e * 3 + a];
#pragma unroll
    for (int k = 0; k < 9; ++k) a2[k] = ea2[(size_t)e * 9 + k];

    float acc0 = 0.f, acc1[3] = {0.f, 0.f, 0.f};
    float acc2[9] = {0.f, 0.f, 0.f, 0.f, 0.f, 0.f, 0.f, 0.f, 0.f};
    edge_contract(acc[0], &acc[1], &acc[4], a0, a1, a2, acc0, acc1, acc2);

    const size_t base = (size_t)send * 32 + c;
    atomicAdd(out0 + base, acc0);
#pragma unroll
    for (int a = 0; a < 3; ++a) atomicAdd(out1 + base * 3 + a, acc1[a]);
#pragma unroll
    for (int k = 0; k < 9; ++k) atomicAdd(out2 + base * 9 + k, acc2[k]);
}

// ---------------------------------------------------------------------------
extern "C" void kernel_launch(void* const* d_in, const int* in_sizes, int n_in,
                              void* d_out, int out_size, void* d_ws, size_t ws_size,
                              hipStream_t stream) {
    const float* h0  = (const float*)d_in[0];
    const float* h1  = (const float*)d_in[1];
    const float* h2  = (const float*)d_in[2];
    // d_in[3] = rel_pos, unused by the math
    const float* ea0 = (const float*)d_in[4];
    const float* ea1 = (const float*)d_in[5];
    const float* ea2 = (const float*)d_in[6];
    const float* W   = (const float*)d_in[7];
    const int*   ei  = (const int*)d_in[8];

    float* out0 = (float*)d_out;                               // [25000][32]
    float* out1 = out0 + (size_t)N_NODES * 32;                 // [25000][32][3]
    float* out2 = out1 + (size_t)N_NODES * 32 * 3;             // [25000][32][3][3]

    char* ws = (char*)d_ws;

    if (ws_size >= WS_NEEDED) {
        char* Hm     = ws;
        int2* slots  = (int2*)(ws + SLOTS_OFF);
        int*  cursor = (int*)(ws + CURSOR_OFF);

        hipMemsetAsync(cursor, 0, (size_t)N_NODES * 4, stream);
        mixscatter_kernel<<<3125 + 782, 256, 0, stream>>>(
            h0, h1, h2, W, ei, Hm, slots, cursor);
        gather_kernel<<<N_NODES / 4, 256, 0, stream>>>(
            Hm, slots, cursor, ea0, ea1, ea2, out0, out1, out2);
    } else {
        hipMemsetAsync(d_out, 0, (size_t)out_size * sizeof(float), stream);
        fused_edge_kernel<<<N_EDGES / 8, 256, 0, stream>>>(
            h0, h1, h2, W, ea0, ea1, ea2, ei, out0, out1, out2);
    }
}

// Round 9
// 93.615 us; speedup vs baseline: 2.1924x; 2.1924x over previous
//
#include <hip/hip_runtime.h>

#define N_NODES 25000
#define N_EDGES 200000
#define NC 32
#define DMAX 64            // bucket capacity; degrees are Poisson(8), max ~25

typedef unsigned int u32;
typedef u32   u32x4 __attribute__((ext_vector_type(4)));
typedef u32   u32x2 __attribute__((ext_vector_type(2)));
typedef float f32x2 __attribute__((ext_vector_type(2)));
typedef float f32x4 __attribute__((ext_vector_type(4)));
// 4-byte-aligned views (HW supports dword-aligned x2/x4 accesses)
typedef u32x4 u32x4_a4 __attribute__((aligned(4)));
typedef u32x2 u32x2_a4 __attribute__((aligned(4)));
typedef f32x2 f32x2_a4 __attribute__((aligned(4)));
typedef f32x4 f32x4_a4 __attribute__((aligned(4)));

// ---------------------------------------------------------------------------
// Workspace layout (bytes)
//   Hm     : [25000][32 ch][14 ushort] bf16, 28 B/row, 896 B/node = 22,400,000
//   slots  : [25000][64] int2                                     = 12,800,000
//   cursor : [25000] int                                          =    100,000
// ---------------------------------------------------------------------------
static constexpr size_t HM_BYTES   = (size_t)N_NODES * NC * 28;        // 22,400,000
static constexpr size_t SLOTS_OFF  = HM_BYTES;
static constexpr size_t CURSOR_OFF = SLOTS_OFF + (size_t)N_NODES * DMAX * 8;
static constexpr size_t WS_NEEDED  = CURSOR_OFF + (size_t)N_NODES * 4; // ~35.3 MB

__device__ __forceinline__ unsigned short f2b(float f) {
    union { float f; unsigned u; } v; v.f = f;
    unsigned r = v.u + 0x7FFFu + ((v.u >> 16) & 1u);
    return (unsigned short)(r >> 16);
}
__device__ __forceinline__ float blo(u32 u) { return __uint_as_float(u << 16); }
__device__ __forceinline__ float bhi(u32 u) { return __uint_as_float(u & 0xFFFF0000u); }

// ---------------------------------------------------------------------------
// Per-edge contraction math (closed form of all einsum terms). Accumulates.
// ---------------------------------------------------------------------------
__device__ __forceinline__ void edge_contract(
    float H0v, const float H1v[3], const float H2v[9],
    float a0, const float a1[3], const float a2[9],
    float& acc0, float acc1[3], float acc2[9])
{
    const float t2 = a2[0] + a2[4] + a2[8];
    const float T2 = H2v[0] + H2v[4] + H2v[8];
    const float s  = a0 + t2;
    const float G  = H0v + T2;

    float sA[9], S2[9];
#pragma unroll
    for (int a = 0; a < 3; ++a)
#pragma unroll
        for (int b = 0; b < 3; ++b) {
            sA[a*3+b] = a2[a*3+b] + a2[b*3+a];
            S2[a*3+b] = H2v[a*3+b] + H2v[b*3+a];
        }

    float v0 = G * s;
#pragma unroll
    for (int a = 0; a < 3; ++a) v0 += H1v[a] * a1[a];
#pragma unroll
    for (int k = 0; k < 9; ++k) v0 += H2v[k] * sA[k];
    acc0 += v0;

#pragma unroll
    for (int a = 0; a < 3; ++a) {
        float v = G * a1[a] + H1v[a] * s;
#pragma unroll
        for (int b = 0; b < 3; ++b)
            v += sA[a*3+b] * H1v[b] + S2[a*3+b] * a1[b];
        acc1[a] += v;
    }

#pragma unroll
    for (int a = 0; a < 3; ++a)
#pragma unroll
        for (int b = 0; b < 3; ++b) {
            float v = G * a2[a*3+b] + H1v[a] * a1[b] + H2v[a*3+b] * s;
#pragma unroll
            for (int d = 0; d < 3; ++d)
                v += S2[a*3+d] * sA[d*3+b];
            acc2[a*3+b] += v;
        }
}

// ---------------------------------------------------------------------------
// Fused kernel: blocks [0,3125) = per-node channel mixing -> bf16 Hm
//               blocks [3125,3907) = bucket scatter of edges by send node
// cursor[] must be zeroed before this kernel (hipMemsetAsync).
// ---------------------------------------------------------------------------
__global__ __launch_bounds__(256) void mixscatter_kernel(
    const float* __restrict__ h0, const float* __restrict__ h1,
    const float* __restrict__ h2, const float* __restrict__ W,
    const int* __restrict__ ei,
    char* __restrict__ Hm, int2* __restrict__ slots, int* __restrict__ cursor)
{
    const int tid = threadIdx.x;

    if (blockIdx.x >= 3125) {            // ---- scatter part ----
        const int e = (blockIdx.x - 3125) * 256 + tid;
        if (e < N_EDGES) {
            const int send = ei[e];
            const int pos  = atomicAdd(&cursor[send], 1);
            if (pos < DMAX) {            // Poisson(8): deg>64 has P~1e-40
                int2 sl; sl.x = e; sl.y = ei[N_EDGES + e];
                slots[send * DMAX + pos] = sl;
            }
        }
        return;
    }

    // ---- mix part ----
    __shared__ float Wt[3 * 32 * 32];    // Wt[r][j][i] = W[r][i][j]
    __shared__ float h_lds[8 * 417];     // [node][j*13 + p]

    const int n0 = blockIdx.x * 8;

#pragma unroll
    for (int k = 0; k < 12; ++k) {
        int q = tid + k * 256;           // q = r*1024 + j*32 + i
        int r = q >> 10;
        int j = (q >> 5) & 31;
        int i = q & 31;
        Wt[q] = W[r * 1024 + i * 32 + j];
    }

    {
        int idx = tid;                   // h0: 256 floats
        h_lds[(idx >> 5) * 417 + (idx & 31) * 13 + 0] = h0[(size_t)n0 * 32 + idx];
    }
#pragma unroll
    for (int k = 0; k < 3; ++k) {        // h1: 768 floats
        int idx = tid + k * 256;
        int ln = idx / 96, rem = idx % 96;
        h_lds[ln * 417 + (rem / 3) * 13 + 1 + (rem % 3)] = h1[(size_t)n0 * 96 + idx];
    }
#pragma unroll
    for (int k = 0; k < 9; ++k) {        // h2: 2304 floats
        int idx = tid + k * 256;
        int ln = idx / 288, rem = idx % 288;
        h_lds[ln * 417 + (rem / 9) * 13 + 4 + (rem % 9)] = h2[(size_t)n0 * 288 + idx];
    }
    __syncthreads();

    const int ln = tid >> 5;
    const int i  = tid & 31;
    const int n  = n0 + ln;

    float acc[13];
#pragma unroll
    for (int p = 0; p < 13; ++p) acc[p] = 0.f;

#pragma unroll 4
    for (int j = 0; j < 32; ++j) {
        const float w0 = Wt[          j * 32 + i];
        const float w1 = Wt[1024 +    j * 32 + i];
        const float w2 = Wt[2048 +    j * 32 + i];
        const float* hv = &h_lds[ln * 417 + j * 13];
        acc[0] += w0 * hv[0];
#pragma unroll
        for (int p = 0; p < 3; ++p) acc[1 + p] += w1 * hv[1 + p];
#pragma unroll
        for (int p = 0; p < 9; ++p) acc[4 + p] += w2 * hv[4 + p];
    }

    // pack 13 bf16 into 28-B channel-major row
    unsigned short b[13];
#pragma unroll
    for (int p = 0; p < 13; ++p) b[p] = f2b(acc[p]);
    u32 w0 = (u32)b[0]  | ((u32)b[1]  << 16);
    u32 w1 = (u32)b[2]  | ((u32)b[3]  << 16);
    u32 w2 = (u32)b[4]  | ((u32)b[5]  << 16);
    u32 w3 = (u32)b[6]  | ((u32)b[7]  << 16);
    u32 w4 = (u32)b[8]  | ((u32)b[9]  << 16);
    u32 w5 = (u32)b[10] | ((u32)b[11] << 16);
    u32 w6 = (u32)b[12];

    char* dst = Hm + (size_t)n * 896 + i * 28;
    u32x4 q0; q0.x = w0; q0.y = w1; q0.z = w2; q0.w = w3;
    u32x2 q1; q1.x = w4; q1.y = w5;
    *(u32x4_a4*)dst        = q0;
    *(u32x2_a4*)(dst + 16) = q1;
    *(u32*)(dst + 24)      = w6;
}

// ---------------------------------------------------------------------------
// Gather: one WAVE per node; lane = channel + 32*par; par ∈ {0,1} walks
// alternating bucket slots; 13 shfl_xor(32) combines at the end.
// Plain loop. NOTE (r7): explicit SW pipeline regressed (VGPR 48->56, -12%).
// NOTE (r8): __launch_bounds__(256,8) regressed 3x — forced 32 VGPR, spilled
// acc2/a2/H2v to scratch (WRITE_SIZE 40MB->457MB). Keep the default bound.
// Writes every output element exactly once (no zeroing of d_out needed).
// ---------------------------------------------------------------------------
__global__ __launch_bounds__(256) void gather_kernel(
    const char* __restrict__ Hm, const int2* __restrict__ slots,
    const int* __restrict__ cursor,
    const float* __restrict__ ea0, const float* __restrict__ ea1,
    const float* __restrict__ ea2,
    float* __restrict__ out0, float* __restrict__ out1, float* __restrict__ out2)
{
    const int n    = blockIdx.x * 4 + (threadIdx.x >> 6);
    const int lane = threadIdx.x & 63;
    const int c    = lane & 31;
    const int par  = lane >> 5;

    const int draw = cursor[n];
    const int d    = draw < DMAX ? draw : DMAX;
    const int2* sb = slots + (u32)n * DMAX;
    const u32 c28  = (u32)c * 28u;

    float acc0 = 0.f, acc1[3] = {0.f, 0.f, 0.f};
    float acc2[9] = {0.f, 0.f, 0.f, 0.f, 0.f, 0.f, 0.f, 0.f, 0.f};

#pragma unroll 1
    for (int i = par; i < d; i += 2) {
        const int2 sl  = sb[i];
        const u32  e   = (u32)sl.x;

        // 28-B bf16 Hm row, 3 wide loads (u32 offset math)
        const char* hmp = Hm + ((u32)sl.y * 896u + c28);
        const u32x4 q0 = *(const u32x4_a4*)hmp;
        const u32x2 q1 = *(const u32x2_a4*)(hmp + 16);
        const u32   q2 = *(const u32*)(hmp + 24);

        const float H0v = blo(q0.x);
        float H1v[3], H2v[9];
        H1v[0] = bhi(q0.x); H1v[1] = blo(q0.y); H1v[2] = bhi(q0.y);
        H2v[0] = blo(q0.z); H2v[1] = bhi(q0.z); H2v[2] = blo(q0.w);
        H2v[3] = bhi(q0.w); H2v[4] = blo(q1.x); H2v[5] = bhi(q1.x);
        H2v[6] = blo(q1.y); H2v[7] = bhi(q1.y); H2v[8] = blo(q2);

        const float a0 = ea0[e];
        float a1[3], a2[9];
        {
            const f32x2 v = *(const f32x2_a4*)(ea1 + e * 3u);
            a1[0] = v.x; a1[1] = v.y; a1[2] = ea1[e * 3u + 2u];
            const f32x4 b0 = *(const f32x4_a4*)(ea2 + e * 9u);
            const f32x4 b1 = *(const f32x4_a4*)(ea2 + e * 9u + 4u);
            a2[0] = b0.x; a2[1] = b0.y; a2[2] = b0.z; a2[3] = b0.w;
            a2[4] = b1.x; a2[5] = b1.y; a2[6] = b1.z; a2[7] = b1.w;
            a2[8] = ea2[e * 9u + 8u];
        }

        edge_contract(H0v, H1v, H2v, a0, a1, a2, acc0, acc1, acc2);
    }

    // combine par=0 / par=1 halves
    acc0 += __shfl_xor(acc0, 32);
#pragma unroll
    for (int a = 0; a < 3; ++a) acc1[a] += __shfl_xor(acc1[a], 32);
#pragma unroll
    for (int k = 0; k < 9; ++k) acc2[k] += __shfl_xor(acc2[k], 32);

    if (par == 0) {
        const u32 base = (u32)n * 32u + (u32)c;
        out0[base] = acc0;
        // out1: 3 contiguous floats per lane
        f32x2 o1; o1.x = acc1[0]; o1.y = acc1[1];
        *(f32x2_a4*)(out1 + base * 3u) = o1;
        out1[base * 3u + 2u] = acc1[2];
        // out2: 9 contiguous floats per lane
        f32x4 oa; oa.x = acc2[0]; oa.y = acc2[1]; oa.z = acc2[2]; oa.w = acc2[3];
        f32x4 ob; ob.x = acc2[4]; ob.y = acc2[5]; ob.z = acc2[6]; ob.w = acc2[7];
        *(f32x4_a4*)(out2 + base * 9u)      = oa;
        *(f32x4_a4*)(out2 + base * 9u + 4u) = ob;
        out2[base * 9u + 8u] = acc2[8];
    }
}

// ---------------------------------------------------------------------------
// Fallback (no workspace): fused per-edge mixing + contraction + atomics
// ---------------------------------------------------------------------------
__global__ __launch_bounds__(256) void fused_edge_kernel(
    const float* __restrict__ h0, const float* __restrict__ h1,
    const float* __restrict__ h2, const float* __restrict__ W,
    const float* __restrict__ ea0, const float* __restrict__ ea1,
    const float* __restrict__ ea2, const int* __restrict__ ei,
    float* __restrict__ out0, float* __restrict__ out1, float* __restrict__ out2)
{
    __shared__ float Wt[3 * 32 * 32];
    __shared__ float h_lds[8 * 417];

    const int tid = threadIdx.x;
#pragma unroll
    for (int k = 0; k < 12; ++k) {
        int q = tid + k * 256;
        int r = q >> 10;
        int j = (q >> 5) & 31;
        int i = q & 31;
        Wt[q] = W[r * 1024 + i * 32 + j];
    }

    const int g = tid >> 5;
    const int c = tid & 31;
    const int e = blockIdx.x * 8 + g;
    const int send = ei[e];
    const int recv = ei[N_EDGES + e];

    h_lds[g * 417 + c * 13 + 0] = h0[(size_t)recv * 32 + c];
#pragma unroll
    for (int a = 0; a < 3; ++a)
        h_lds[g * 417 + c * 13 + 1 + a] = h1[(size_t)recv * 96 + c * 3 + a];
#pragma unroll
    for (int k = 0; k < 9; ++k)
        h_lds[g * 417 + c * 13 + 4 + k] = h2[(size_t)recv * 288 + c * 9 + k];
    __syncthreads();

    float acc[13];
#pragma unroll
    for (int p = 0; p < 13; ++p) acc[p] = 0.f;
#pragma unroll 4
    for (int j = 0; j < 32; ++j) {
        const float w0 = Wt[          j * 32 + c];
        const float w1 = Wt[1024 +    j * 32 + c];
        const float w2 = Wt[2048 +    j * 32 + c];
        const float* hv = &h_lds[g * 417 + j * 13];
        acc[0] += w0 * hv[0];
#pragma unroll
        for (int p = 0; p < 3; ++p) acc[1 + p] += w1 * hv[1 + p];
#pragma unroll
        for (int p = 0; p < 9; ++p) acc[4 + p] += w2 * hv[4 + p];
    }

    const float a0 = ea0[e];
    float a1[3], a2[9];
#pragma unroll
    for (int a = 0; a < 3; ++a) a1[a] = ea1[(size_t)e * 3 + a];
#pragma unroll
    for (int k = 0; k < 9; ++k) a2[k] = ea2[(size_t)e * 9 + k];

    float acc0 = 0.f, acc1[3] = {0.f, 0.f, 0.f};
    float acc2[9] = {0.f, 0.f, 0.f, 0.f, 0.f, 0.f, 0.f, 0.f, 0.f};
    edge_contract(acc[0], &acc[1], &acc[4], a0, a1, a2, acc0, acc1, acc2);

    const size_t base = (size_t)send * 32 + c;
    atomicAdd(out0 + base, acc0);
#pragma unroll
    for (int a = 0; a < 3; ++a) atomicAdd(out1 + base * 3 + a, acc1[a]);
#pragma unroll
    for (int k = 0; k < 9; ++k) atomicAdd(out2 + base * 9 + k, acc2[k]);
}

// ---------------------------------------------------------------------------
extern "C" void kernel_launch(void* const* d_in, const int* in_sizes, int n_in,
                              void* d_out, int out_size, void* d_ws, size_t ws_size,
                              hipStream_t stream) {
    const float* h0  = (const float*)d_in[0];
    const float* h1  = (const float*)d_in[1];
    const float* h2  = (const float*)d_in[2];
    // d_in[3] = rel_pos, unused by the math
    const float* ea0 = (const float*)d_in[4];
    const float* ea1 = (const float*)d_in[5];
    const float* ea2 = (const float*)d_in[6];
    const float* W   = (const float*)d_in[7];
    const int*   ei  = (const int*)d_in[8];

    float* out0 = (float*)d_out;                               // [25000][32]
    float* out1 = out0 + (size_t)N_NODES * 32;                 // [25000][32][3]
    float* out2 = out1 + (size_t)N_NODES * 32 * 3;             // [25000][32][3][3]

    char* ws = (char*)d_ws;

    if (ws_size >= WS_NEEDED) {
        char* Hm     = ws;
        int2* slots  = (int2*)(ws + SLOTS_OFF);
        int*  cursor = (int*)(ws + CURSOR_OFF);

        hipMemsetAsync(cursor, 0, (size_t)N_NODES * 4, stream);
        mixscatter_kernel<<<3125 + 782, 256, 0, stream>>>(
            h0, h1, h2, W, ei, Hm, slots, cursor);
        gather_kernel<<<N_NODES / 4, 256, 0, stream>>>(
            Hm, slots, cursor, ea0, ea1, ea2, out0, out1, out2);
    } else {
        hipMemsetAsync(d_out, 0, (size_t)out_size * sizeof(float), stream);
        fused_edge_kernel<<<N_EDGES / 8, 256, 0, stream>>>(
            h0, h1, h2, W, ea0, ea1, ea2, ei, out0, out1, out2);
    }
}

// Round 10
// 89.480 us; speedup vs baseline: 2.2937x; 1.0462x over previous
//
#include <hip/hip_runtime.h>

#define N_NODES 25000
#define N_EDGES 200000
#define NC 32
#define DMAX 64            // bucket capacity; degrees are Poisson(8), max ~25

typedef unsigned int u32;
typedef u32   u32x4 __attribute__((ext_vector_type(4)));
typedef u32   u32x2 __attribute__((ext_vector_type(2)));
typedef float f32x2 __attribute__((ext_vector_type(2)));
typedef float f32x4 __attribute__((ext_vector_type(4)));
typedef u32x4 u32x4_a4 __attribute__((aligned(4)));
typedef u32x2 u32x2_a4 __attribute__((aligned(4)));
typedef f32x2 f32x2_a4 __attribute__((aligned(4)));
typedef f32x4 f32x4_a4 __attribute__((aligned(4)));

// ---------------------------------------------------------------------------
// Workspace layout (bytes)
//   Hm     : [25000][32 ch][14 ushort] bf16 (slot0 = G = H0+tr(H2))
//   slots  : [25000][64] int2   (.x = edge id, .y = recv id)
//   cursor : [25000] int
// ---------------------------------------------------------------------------
static constexpr size_t HM_BYTES   = (size_t)N_NODES * NC * 28;        // 22,400,000
static constexpr size_t SLOTS_OFF  = HM_BYTES;
static constexpr size_t CURSOR_OFF = SLOTS_OFF + (size_t)N_NODES * DMAX * 8;
static constexpr size_t WS_NEEDED  = CURSOR_OFF + (size_t)N_NODES * 4; // ~35.3 MB

__device__ __forceinline__ unsigned short f2b(float f) {
    union { float f; unsigned u; } v; v.f = f;
    unsigned r = v.u + 0x7FFFu + ((v.u >> 16) & 1u);
    return (unsigned short)(r >> 16);
}
__device__ __forceinline__ float blo(u32 u) { return __uint_as_float(u << 16); }
__device__ __forceinline__ float bhi(u32 u) { return __uint_as_float(u & 0xFFFF0000u); }

// ---------------------------------------------------------------------------
// Per-edge contraction, G-form (G = H0 + tr(H2) precomputed at mix time)
// ---------------------------------------------------------------------------
__device__ __forceinline__ void edge_contract_g(
    float G, const float H1v[3], const float H2v[9],
    float a0, const float a1[3], const float a2[9],
    float& acc0, float acc1[3], float acc2[9])
{
    const float t2 = a2[0] + a2[4] + a2[8];
    const float s  = a0 + t2;

    float sA[9], S2[9];
#pragma unroll
    for (int a = 0; a < 3; ++a)
#pragma unroll
        for (int b = 0; b < 3; ++b) {
            sA[a*3+b] = a2[a*3+b] + a2[b*3+a];
            S2[a*3+b] = H2v[a*3+b] + H2v[b*3+a];
        }

    float v0 = G * s;
#pragma unroll
    for (int a = 0; a < 3; ++a) v0 += H1v[a] * a1[a];
#pragma unroll
    for (int k = 0; k < 9; ++k) v0 += H2v[k] * sA[k];
    acc0 += v0;

#pragma unroll
    for (int a = 0; a < 3; ++a) {
        float v = G * a1[a] + H1v[a] * s;
#pragma unroll
        for (int b = 0; b < 3; ++b)
            v += sA[a*3+b] * H1v[b] + S2[a*3+b] * a1[b];
        acc1[a] += v;
    }

#pragma unroll
    for (int a = 0; a < 3; ++a)
#pragma unroll
        for (int b = 0; b < 3; ++b) {
            float v = G * a2[a*3+b] + H1v[a] * a1[b] + H2v[a*3+b] * s;
#pragma unroll
            for (int d = 0; d < 3; ++d)
                v += S2[a*3+d] * sA[d*3+b];
            acc2[a*3+b] += v;
        }
}

// original form for the no-workspace fallback
__device__ __forceinline__ void edge_contract(
    float H0v, const float H1v[3], const float H2v[9],
    float a0, const float a1[3], const float a2[9],
    float& acc0, float acc1[3], float acc2[9])
{
    const float T2 = H2v[0] + H2v[4] + H2v[8];
    edge_contract_g(H0v + T2, H1v, H2v, a0, a1, a2, acc0, acc1, acc2);
}

// ---------------------------------------------------------------------------
// Fused kernel: blocks [0,3125) = per-node channel mixing -> bf16 Hm
//               blocks [3125,3907) = bucket scatter of edges by send node
// cursor[] must be zeroed before this kernel (hipMemsetAsync).
// h_lds stride 16 (was 13/417): hv read as 3x ds_read_b128 + 1 scalar per j
// instead of 13 scalar ds_read_b32 (mix was LDS-instruction-bound, r9).
// ---------------------------------------------------------------------------
__global__ __launch_bounds__(256) void mixscatter_kernel(
    const float* __restrict__ h0, const float* __restrict__ h1,
    const float* __restrict__ h2, const float* __restrict__ W,
    const int* __restrict__ ei,
    char* __restrict__ Hm, int2* __restrict__ slots, int* __restrict__ cursor)
{
    const int tid = threadIdx.x;

    if (blockIdx.x >= 3125) {            // ---- scatter part ----
        const int e = (blockIdx.x - 3125) * 256 + tid;
        if (e < N_EDGES) {
            const int send = ei[e];
            const int pos  = atomicAdd(&cursor[send], 1);
            if (pos < DMAX) {            // Poisson(8): deg>64 has P~1e-40
                int2 sl; sl.x = e; sl.y = ei[N_EDGES + e];
                slots[send * DMAX + pos] = sl;
            }
        }
        return;
    }

    // ---- mix part ----
    __shared__ float Wt[3 * 32 * 32];                 // Wt[r][j][i] = W[r][i][j]
    __shared__ __align__(16) float h_lds[8 * 512];    // [node][j*16 + p], p<13

    const int n0 = blockIdx.x * 8;

#pragma unroll
    for (int k = 0; k < 12; ++k) {
        int q = tid + k * 256;           // q = r*1024 + j*32 + i
        int r = q >> 10;
        int j = (q >> 5) & 31;
        int i = q & 31;
        Wt[q] = W[r * 1024 + i * 32 + j];
    }

    {
        int idx = tid;                   // h0: 256 floats
        h_lds[(idx >> 5) * 512 + (idx & 31) * 16 + 0] = h0[(size_t)n0 * 32 + idx];
    }
#pragma unroll
    for (int k = 0; k < 3; ++k) {        // h1: 768 floats
        int idx = tid + k * 256;
        int ln = idx / 96, rem = idx % 96;
        h_lds[ln * 512 + (rem / 3) * 16 + 1 + (rem % 3)] = h1[(size_t)n0 * 96 + idx];
    }
#pragma unroll
    for (int k = 0; k < 9; ++k) {        // h2: 2304 floats
        int idx = tid + k * 256;
        int ln = idx / 288, rem = idx % 288;
        h_lds[ln * 512 + (rem / 9) * 16 + 4 + (rem % 9)] = h2[(size_t)n0 * 288 + idx];
    }
    __syncthreads();

    const int ln = tid >> 5;
    const int i  = tid & 31;
    const int n  = n0 + ln;

    float acc[13];
#pragma unroll
    for (int p = 0; p < 13; ++p) acc[p] = 0.f;

#pragma unroll 4
    for (int j = 0; j < 32; ++j) {
        const float w0 = Wt[          j * 32 + i];
        const float w1 = Wt[1024 +    j * 32 + i];
        const float w2 = Wt[2048 +    j * 32 + i];
        const float* hv = &h_lds[ln * 512 + j * 16];
        const f32x4 qa = *(const f32x4*)(hv);        // p 0..3
        const f32x4 qb = *(const f32x4*)(hv + 4);    // p 4..7
        const f32x4 qc = *(const f32x4*)(hv + 8);    // p 8..11
        const float hc = hv[12];                     // p 12
        acc[0]  += w0 * qa.x;
        acc[1]  += w1 * qa.y;  acc[2]  += w1 * qa.z;  acc[3]  += w1 * qa.w;
        acc[4]  += w2 * qb.x;  acc[5]  += w2 * qb.y;  acc[6]  += w2 * qb.z;
        acc[7]  += w2 * qb.w;  acc[8]  += w2 * qc.x;  acc[9]  += w2 * qc.y;
        acc[10] += w2 * qc.z;  acc[11] += w2 * qc.w;  acc[12] += w2 * hc;
    }

    // fold trace: slot 0 holds G = H0 + tr(H2)
    acc[0] += acc[4] + acc[8] + acc[12];

    // pack 13 bf16 into 28-B channel-major row
    unsigned short b[13];
#pragma unroll
    for (int p = 0; p < 13; ++p) b[p] = f2b(acc[p]);
    u32 w0 = (u32)b[0]  | ((u32)b[1]  << 16);
    u32 w1 = (u32)b[2]  | ((u32)b[3]  << 16);
    u32 w2 = (u32)b[4]  | ((u32)b[5]  << 16);
    u32 w3 = (u32)b[6]  | ((u32)b[7]  << 16);
    u32 w4 = (u32)b[8]  | ((u32)b[9]  << 16);
    u32 w5 = (u32)b[10] | ((u32)b[11] << 16);
    u32 w6 = (u32)b[12];

    char* dst = Hm + (size_t)n * 896 + i * 28;
    u32x4 q0; q0.x = w0; q0.y = w1; q0.z = w2; q0.w = w3;
    u32x2 q1; q1.x = w4; q1.y = w5;
    *(u32x4_a4*)dst        = q0;
    *(u32x2_a4*)(dst + 16) = q1;
    *(u32*)(dst + 24)      = w6;
}

// ---------------------------------------------------------------------------
// Gather: one WAVE per node, TWO nodes per 128-thread block (r9: 4-node
// blocks had max-of-4 Poisson degree imbalance -> 36% occupancy; 2-node
// blocks cut the tail). lane = channel + 32*par; par walks alternating
// slots; 13 shfl_xor(32) combine. Each output written exactly once.
// NOTE (r7): explicit SW pipeline regressed (VGPR 48->56). NOTE (r8):
// __launch_bounds__ min-waves clause forced 32 VGPR + scratch spill (3x).
// ---------------------------------------------------------------------------
__global__ __launch_bounds__(128) void gather_kernel(
    const char* __restrict__ Hm, const int2* __restrict__ slots,
    const int* __restrict__ cursor,
    const float* __restrict__ ea0, const float* __restrict__ ea1,
    const float* __restrict__ ea2,
    float* __restrict__ out0, float* __restrict__ out1, float* __restrict__ out2)
{
    const int n    = blockIdx.x * 2 + (threadIdx.x >> 6);
    const int lane = threadIdx.x & 63;
    const int c    = lane & 31;
    const int par  = lane >> 5;

    const int draw = cursor[n];
    const int d    = draw < DMAX ? draw : DMAX;
    const int2* sb = slots + (u32)n * DMAX;
    const u32 c28  = (u32)c * 28u;

    float acc0 = 0.f, acc1[3] = {0.f, 0.f, 0.f};
    float acc2[9] = {0.f, 0.f, 0.f, 0.f, 0.f, 0.f, 0.f, 0.f, 0.f};

#pragma unroll 1
    for (int i = par; i < d; i += 2) {
        const int2 sl  = sb[i];
        const u32  e   = (u32)sl.x;

        // 28-B bf16 Hm row, 3 wide loads (u32 offset math)
        const char* hmp = Hm + ((u32)sl.y * 896u + c28);
        const u32x4 q0 = *(const u32x4_a4*)hmp;
        const u32x2 q1 = *(const u32x2_a4*)(hmp + 16);
        const u32   q2 = *(const u32*)(hmp + 24);

        const float Gv = blo(q0.x);                  // slot0 = G
        float H1v[3], H2v[9];
        H1v[0] = bhi(q0.x); H1v[1] = blo(q0.y); H1v[2] = bhi(q0.y);
        H2v[0] = blo(q0.z); H2v[1] = bhi(q0.z); H2v[2] = blo(q0.w);
        H2v[3] = bhi(q0.w); H2v[4] = blo(q1.x); H2v[5] = bhi(q1.x);
        H2v[6] = blo(q1.y); H2v[7] = bhi(q1.y); H2v[8] = blo(q2);

        const float a0 = ea0[e];
        float a1[3], a2[9];
        {
            const f32x2 v = *(const f32x2_a4*)(ea1 + e * 3u);
            a1[0] = v.x; a1[1] = v.y; a1[2] = ea1[e * 3u + 2u];
            const f32x4 b0 = *(const f32x4_a4*)(ea2 + e * 9u);
            const f32x4 b1 = *(const f32x4_a4*)(ea2 + e * 9u + 4u);
            a2[0] = b0.x; a2[1] = b0.y; a2[2] = b0.z; a2[3] = b0.w;
            a2[4] = b1.x; a2[5] = b1.y; a2[6] = b1.z; a2[7] = b1.w;
            a2[8] = ea2[e * 9u + 8u];
        }

        edge_contract_g(Gv, H1v, H2v, a0, a1, a2, acc0, acc1, acc2);
    }

    // combine par=0 / par=1 halves
    acc0 += __shfl_xor(acc0, 32);
#pragma unroll
    for (int a = 0; a < 3; ++a) acc1[a] += __shfl_xor(acc1[a], 32);
#pragma unroll
    for (int k = 0; k < 9; ++k) acc2[k] += __shfl_xor(acc2[k], 32);

    if (par == 0) {
        const u32 base = (u32)n * 32u + (u32)c;
        out0[base] = acc0;
        f32x2 o1; o1.x = acc1[0]; o1.y = acc1[1];
        *(f32x2_a4*)(out1 + base * 3u) = o1;
        out1[base * 3u + 2u] = acc1[2];
        f32x4 oa; oa.x = acc2[0]; oa.y = acc2[1]; oa.z = acc2[2]; oa.w = acc2[3];
        f32x4 ob; ob.x = acc2[4]; ob.y = acc2[5]; ob.z = acc2[6]; ob.w = acc2[7];
        *(f32x4_a4*)(out2 + base * 9u)      = oa;
        *(f32x4_a4*)(out2 + base * 9u + 4u) = ob;
        out2[base * 9u + 8u] = acc2[8];
    }
}

// ---------------------------------------------------------------------------
// Fallback (no workspace): fused per-edge mixing + contraction + atomics
// ---------------------------------------------------------------------------
__global__ __launch_bounds__(256) void fused_edge_kernel(
    const float* __restrict__ h0, const float* __restrict__ h1,
    const float* __restrict__ h2, const float* __restrict__ W,
    const float* __restrict__ ea0, const float* __restrict__ ea1,
    const float* __restrict__ ea2, const int* __restrict__ ei,
    float* __restrict__ out0, float* __restrict__ out1, float* __restrict__ out2)
{
    __shared__ float Wt[3 * 32 * 32];
    __shared__ float h_lds[8 * 417];

    const int tid = threadIdx.x;
#pragma unroll
    for (int k = 0; k < 12; ++k) {
        int q = tid + k * 256;
        int r = q >> 10;
        int j = (q >> 5) & 31;
        int i = q & 31;
        Wt[q] = W[r * 1024 + i * 32 + j];
    }

    const int g = tid >> 5;
    const int c = tid & 31;
    const int e = blockIdx.x * 8 + g;
    const int send = ei[e];
    const int recv = ei[N_EDGES + e];

    h_lds[g * 417 + c * 13 + 0] = h0[(size_t)recv * 32 + c];
#pragma unroll
    for (int a = 0; a < 3; ++a)
        h_lds[g * 417 + c * 13 + 1 + a] = h1[(size_t)recv * 96 + c * 3 + a];
#pragma unroll
    for (int k = 0; k < 9; ++k)
        h_lds[g * 417 + c * 13 + 4 + k] = h2[(size_t)recv * 288 + c * 9 + k];
    __syncthreads();

    float acc[13];
#pragma unroll
    for (int p = 0; p < 13; ++p) acc[p] = 0.f;
#pragma unroll 4
    for (int j = 0; j < 32; ++j) {
        const float w0 = Wt[          j * 32 + c];
        const float w1 = Wt[1024 +    j * 32 + c];
        const float w2 = Wt[2048 +    j * 32 + c];
        const float* hv = &h_lds[g * 417 + j * 13];
        acc[0] += w0 * hv[0];
#pragma unroll
        for (int p = 0; p < 3; ++p) acc[1 + p] += w1 * hv[1 + p];
#pragma unroll
        for (int p = 0; p < 9; ++p) acc[4 + p] += w2 * hv[4 + p];
    }

    const float a0 = ea0[e];
    float a1[3], a2[9];
#pragma unroll
    for (int a = 0; a < 3; ++a) a1[a] = ea1[(size_t)e * 3 + a];
#pragma unroll
    for (int k = 0; k < 9; ++k) a2[k] = ea2[(size_t)e * 9 + k];

    float acc0 = 0.f, acc1[3] = {0.f, 0.f, 0.f};
    float acc2[9] = {0.f, 0.f, 0.f, 0.f, 0.f, 0.f, 0.f, 0.f, 0.f};
    edge_contract(acc[0], &acc[1], &acc[4], a0, a1, a2, acc0, acc1, acc2);

    const size_t base = (size_t)send * 32 + c;
    atomicAdd(out0 + base, acc0);
#pragma unroll
    for (int a = 0; a < 3; ++a) atomicAdd(out1 + base * 3 + a, acc1[a]);
#pragma unroll
    for (int k = 0; k < 9; ++k) atomicAdd(out2 + base * 9 + k, acc2[k]);
}

// ---------------------------------------------------------------------------
extern "C" void kernel_launch(void* const* d_in, const int* in_sizes, int n_in,
                              void* d_out, int out_size, void* d_ws, size_t ws_size,
                              hipStream_t stream) {
    const float* h0  = (const float*)d_in[0];
    const float* h1  = (const float*)d_in[1];
    const float* h2  = (const float*)d_in[2];
    // d_in[3] = rel_pos, unused by the math
    const float* ea0 = (const float*)d_in[4];
    const float* ea1 = (const float*)d_in[5];
    const float* ea2 = (const float*)d_in[6];
    const float* W   = (const float*)d_in[7];
    const int*   ei  = (const int*)d_in[8];

    float* out0 = (float*)d_out;                               // [25000][32]
    float* out1 = out0 + (size_t)N_NODES * 32;                 // [25000][32][3]
    float* out2 = out1 + (size_t)N_NODES * 32 * 3;             // [25000][32][3][3]

    char* ws = (char*)d_ws;

    if (ws_size >= WS_NEEDED) {
        char* Hm     = ws;
        int2* slots  = (int2*)(ws + SLOTS_OFF);
        int*  cursor = (int*)(ws + CURSOR_OFF);

        hipMemsetAsync(cursor, 0, (size_t)N_NODES * 4, stream);
        mixscatter_kernel<<<3125 + 782, 256, 0, stream>>>(
            h0, h1, h2, W, ei, Hm, slots, cursor);
        gather_kernel<<<N_NODES / 2, 128, 0, stream>>>(
            Hm, slots, cursor, ea0, ea1, ea2, out0, out1, out2);
    } else {
        hipMemsetAsync(d_out, 0, (size_t)out_size * sizeof(float), stream);
        fused_edge_kernel<<<N_EDGES / 8, 256, 0, stream>>>(
            h0, h1, h2, W, ea0, ea1, ea2, ei, out0, out1, out2);
    }
}